// Round 1
// baseline (22495.111 us; speedup 1.0000x reference)
//
#include <hip/hip_runtime.h>
#include <math.h>

#define B_TOT 4096
#define TE 168
#define TD 24
#define XDIM 8
#define HDIM 64

// Workspace layout (float offsets). Packed weights: P[k][hid][q] with q in
// {i,f,g,o}; lane (=hid) reads consecutive float4 -> perfectly coalesced.
#define OFF_P0X 0
#define OFF_P0H (OFF_P0X + 8 * 256)    // 2048
#define OFF_P1X (OFF_P0H + 64 * 256)   // 18432
#define OFF_P1H (OFF_P1X + 64 * 256)   // 35...
#define OFF_P2X (OFF_P1H + 64 * 256)
#define OFF_P2H (OFF_P2X + 64 * 256)
#define OFF_PB  (OFF_P2H + 64 * 256)   // biases: 3 * 256
#define OFF_PW  (OFF_PB + 3 * 256)     // w_m[64], w_a[64]
#define WS_FLOATS (OFF_PW + 128)       // 84864 floats = 339456 B

__global__ void pack_kernel(const float* __restrict__ Wih0, const float* __restrict__ Whh0,
                            const float* __restrict__ b0,
                            const float* __restrict__ Wih1, const float* __restrict__ Whh1,
                            const float* __restrict__ b1,
                            const float* __restrict__ Wih2, const float* __restrict__ Whh2,
                            const float* __restrict__ b2,
                            const float* __restrict__ w_m, const float* __restrict__ w_a,
                            float* __restrict__ ws)
{
    const int j = threadIdx.x;       // gate row 0..255  (q*64 + hid)
    const int k = blockIdx.x;        // input column / special slots
    const int q = j >> 6;
    const int hid = j & 63;
    const int dst = (k * 64 + hid) * 4 + q;
    if (k < 8)  ws[OFF_P0X + dst] = Wih0[j * 8 + k];
    if (k < 64) {
        ws[OFF_P0H + dst] = Whh0[j * 64 + k];
        ws[OFF_P1X + dst] = Wih1[j * 64 + k];
        ws[OFF_P1H + dst] = Whh1[j * 64 + k];
        ws[OFF_P2X + dst] = Wih2[j * 64 + k];
        ws[OFF_P2H + dst] = Whh2[j * 64 + k];
    }
    if (k == 64) ws[OFF_PB + 0 * 256 + hid * 4 + q] = b0[j];
    if (k == 65) ws[OFF_PB + 1 * 256 + hid * 4 + q] = b1[j];
    if (k == 66) ws[OFF_PB + 2 * 256 + hid * 4 + q] = b2[j];
    if (k == 67 && j < 64) { ws[OFF_PW + j] = w_m[j]; ws[OFF_PW + 64 + j] = w_a[j]; }
}

__device__ __forceinline__ float sigf(float x)      { return 1.f / (1.f + __expf(-x)); }
__device__ __forceinline__ float tanhfast(float x)  { return 1.f - 2.f / (__expf(2.f * x) + 1.f); }
__device__ __forceinline__ float softplusf(float x) { return fmaxf(x, 0.f) + log1pf(__expf(-fabsf(x))); }

// Accumulate gates for 2 batches over K inputs. wp: packed [K][64] float4.
__device__ __forceinline__ void gate_accum(const float4* __restrict__ wp, int K, int hid,
                                           const float* __restrict__ iA,
                                           const float* __restrict__ iB,
                                           float4& aA, float4& aB)
{
    for (int k4 = 0; k4 < K; k4 += 4) {
        const float4 xa = *(const float4*)(iA + k4);   // LDS broadcast (wave-uniform addr)
        const float4 xb = *(const float4*)(iB + k4);
#pragma unroll
        for (int kk = 0; kk < 4; ++kk) {
            const float4 w = wp[(k4 + kk) * 64 + hid]; // coalesced global (L1/L2-hot)
            const float va = (&xa.x)[kk];
            const float vb = (&xb.x)[kk];
            aA.x += w.x * va; aA.y += w.y * va; aA.z += w.z * va; aA.w += w.w * va;
            aB.x += w.x * vb; aB.y += w.y * vb; aB.z += w.z * vb; aB.w += w.w * vb;
        }
    }
}

__global__ __launch_bounds__(256) void lstm_kernel(
    const float* __restrict__ enc_x, const float* __restrict__ enc_z,
    const float* __restrict__ dec_x, const float* __restrict__ v,
    const float* __restrict__ eps,   const float* __restrict__ ws,
    const float* __restrict__ bmp,   const float* __restrict__ bap,
    float* __restrict__ out)
{
    const int tid = threadIdx.x;
    const int hid = tid & 63;          // lane = hidden unit
    const int wv  = tid >> 6;          // wave 0..3
    const int bg  = blockIdx.x * 8;    // 8 batches per WG
    const int bA = wv, bB = wv + 4;    // two local batches per thread
    const int gA = bg + bA, gB = bg + bB;

    __shared__ __align__(16) float hs[3][8][64];
    __shared__ __align__(16) float xs[8][8];
    __shared__ float zs_s[8];

#pragma unroll
    for (int l = 0; l < 3; ++l) { hs[l][bA][hid] = 0.f; hs[l][bB][hid] = 0.f; }
    float c0A = 0, c0B = 0, c1A = 0, c1B = 0, c2A = 0, c2B = 0;

    const float4* wp0x = (const float4*)(ws + OFF_P0X);
    const float4* wp0h = (const float4*)(ws + OFF_P0H);
    const float4* wp1x = (const float4*)(ws + OFF_P1X);
    const float4* wp1h = (const float4*)(ws + OFF_P1H);
    const float4* wp2x = (const float4*)(ws + OFF_P2X);
    const float4* wp2h = (const float4*)(ws + OFF_P2H);
    const float4 bb0 = *(const float4*)(ws + OFF_PB + hid * 4);
    const float4 bb1 = *(const float4*)(ws + OFF_PB + 256 + hid * 4);
    const float4 bb2 = *(const float4*)(ws + OFF_PB + 512 + hid * 4);
    const float wm = ws[OFF_PW + hid];
    const float wa = ws[OFF_PW + 64 + hid];

    // One LSTM layer for 2 batches. Reads input from iA_/iB_ and recurrent h
    // from hs[l]; sync; writes new h; sync.
    auto layer_fwd = [&](const float4* wx, int Kin, const float4* wh, int l,
                         const float* iA_, const float* iB_,
                         float& cA, float& cB, float& hA, float& hB, const float4& bb) {
        float4 aA = bb, aB = bb;
        gate_accum(wx, Kin, hid, iA_, iB_, aA, aB);
        gate_accum(wh, 64, hid, hs[l][bA], hs[l][bB], aA, aB);
        __syncthreads();   // all reads of hs[l] (and input row) complete
        {
            float i_ = sigf(aA.x), f_ = sigf(aA.y), g_ = tanhfast(aA.z), o_ = sigf(aA.w);
            cA = f_ * cA + i_ * g_;  hA = o_ * tanhfast(cA);
            i_ = sigf(aB.x); f_ = sigf(aB.y); g_ = tanhfast(aB.z); o_ = sigf(aB.w);
            cB = f_ * cB + i_ * g_;  hB = o_ * tanhfast(cB);
        }
        hs[l][bA][hid] = hA; hs[l][bB][hid] = hB;
        __syncthreads();   // new h visible
    };

    // ---------------- encoder ----------------
    for (int t = 0; t < TE; ++t) {
        if (tid < 64) {
            const int bl = tid >> 3, k = tid & 7;
            xs[bl][k] = enc_x[((size_t)(bg + bl) * TE + t) * XDIM + k];
        }
        __syncthreads();
        float h0A, h0B, h1A, h1B, h2A, h2B;
        layer_fwd(wp0x, 8,  wp0h, 0, xs[bA],    xs[bB],    c0A, c0B, h0A, h0B, bb0);
        layer_fwd(wp1x, 64, wp1h, 1, hs[0][bA], hs[0][bB], c1A, c1B, h1A, h1B, bb1);
        layer_fwd(wp2x, 64, wp2h, 2, hs[1][bA], hs[1][bB], c2A, c2B, h2A, h2B, bb2);
    }

    // ---------------- decoder ----------------
    if (tid < 8) zs_s[tid] = enc_z[(size_t)(bg + tid) * TE + (TE - 1)] / v[bg + tid];
    __syncthreads();
    const float bmv = *bmp, bav = *bap;
    const float vfA = v[gA], vfB = v[gB];

    for (int t = 0; t < TD; ++t) {
        if (tid < 64) {
            const int bl = tid >> 3, k = tid & 7;
            xs[bl][k] = (k == 0) ? zs_s[bl]
                                 : dec_x[(size_t)(bg + bl) * (TD * 7) + t * 7 + (k - 1)];
        }
        __syncthreads();
        float h0A, h0B, h1A, h1B, h2A, h2B;
        layer_fwd(wp0x, 8,  wp0h, 0, xs[bA],    xs[bB],    c0A, c0B, h0A, h0B, bb0);
        layer_fwd(wp1x, 64, wp1h, 1, hs[0][bA], hs[0][bB], c1A, c1B, h1A, h1B, bb1);
        layer_fwd(wp2x, 64, wp2h, 2, hs[1][bA], hs[1][bB], c2A, c2B, h2A, h2B, bb2);

        // head: m = (h2 . w_m + b_m)*vf ; a = softplus(h2 . w_a + b_a)*vf
        float pmA = h2A * wm, paA = h2A * wa, pmB = h2B * wm, paB = h2B * wa;
#pragma unroll
        for (int off = 32; off; off >>= 1) {
            pmA += __shfl_xor(pmA, off, 64);
            paA += __shfl_xor(paA, off, 64);
            pmB += __shfl_xor(pmB, off, 64);
            paB += __shfl_xor(paB, off, 64);
        }
        if (hid == 0) {
            const float eA = eps[(size_t)gA * TD + t];
            const float eB = eps[(size_t)gB * TD + t];
            const float mA = (pmA + bmv) * vfA;
            const float aA_ = softplusf(paA + bav) * vfA;
            const float zA = mA + aA_ * eA;
            out[(size_t)gA * TD + t] = zA;  zs_s[bA] = zA / vfA;
            const float mB = (pmB + bmv) * vfB;
            const float aB_ = softplusf(paB + bav) * vfB;
            const float zB = mB + aB_ * eB;
            out[(size_t)gB * TD + t] = zB;  zs_s[bB] = zB / vfB;
        }
        __syncthreads();   // zs_s ready for next staging
    }
}

extern "C" void kernel_launch(void* const* d_in, const int* in_sizes, int n_in,
                              void* d_out, int out_size, void* d_ws, size_t ws_size,
                              hipStream_t stream) {
    const float* enc_x = (const float*)d_in[0];
    const float* enc_z = (const float*)d_in[1];
    const float* dec_x = (const float*)d_in[2];
    const float* v     = (const float*)d_in[3];
    const float* eps   = (const float*)d_in[4];
    const float* Wih0  = (const float*)d_in[5];
    const float* Whh0  = (const float*)d_in[6];
    const float* b0    = (const float*)d_in[7];
    const float* Wih1  = (const float*)d_in[8];
    const float* Whh1  = (const float*)d_in[9];
    const float* b1    = (const float*)d_in[10];
    const float* Wih2  = (const float*)d_in[11];
    const float* Whh2  = (const float*)d_in[12];
    const float* b2    = (const float*)d_in[13];
    const float* w_m   = (const float*)d_in[14];
    const float* b_m   = (const float*)d_in[15];
    const float* w_a   = (const float*)d_in[16];
    const float* b_a   = (const float*)d_in[17];
    float* out = (float*)d_out;
    float* ws  = (float*)d_ws;

    pack_kernel<<<68, 256, 0, stream>>>(Wih0, Whh0, b0, Wih1, Whh1, b1,
                                        Wih2, Whh2, b2, w_m, w_a, ws);
    lstm_kernel<<<B_TOT / 8, 256, 0, stream>>>(enc_x, enc_z, dec_x, v, eps,
                                               ws, b_m, b_a, out);
}

// Round 2
// 602.105 us; speedup vs baseline: 37.3608x; 37.3608x over previous
//
#include <hip/hip_runtime.h>
#include <math.h>

#define B_TOT 4096
#define TE 168
#define TD 24
#define NWG 256          // B_TOT / 16 batches per WG
#define HSTR 72          // padded f16 row stride (144 B = 16B-aligned)

typedef _Float16 f16;
typedef __attribute__((ext_vector_type(8))) _Float16 f16x8;
typedef __attribute__((ext_vector_type(4))) float f32x4;

// ---------------------------------------------------------------------------
// Pack weights into exact MFMA B-fragment order, f16:
//   pk[w][l][q][c][lane][j] = Wcomb_l[q*64 + w*16 + (lane&15)][c*32 + (lane>>4)*8 + j]
// Wcomb per layer (K padded to 32-multiples):
//   l=0 (K=96):  k<8 -> Wih0[.][k];  8<=k<32 -> 0;  32<=k<96 -> Whh0[.][k-32]
//   l=1 (K=128): k<64 -> Wih1[.][k];  else Whh1[.][k-64]
//   l=2 (K=128): k<64 -> Wih2[.][k];  else Whh2[.][k-64]
// c runs 0..3 (layer0 uses only c<3; c==3 slot written 0, never read).
// Total: 4*3*4*4*64*8 = 98304 f16 = 192 KB.
// ---------------------------------------------------------------------------
__global__ __launch_bounds__(256) void pack_kernel(
    const float* __restrict__ Wih0, const float* __restrict__ Whh0,
    const float* __restrict__ Wih1, const float* __restrict__ Whh1,
    const float* __restrict__ Wih2, const float* __restrict__ Whh2,
    f16* __restrict__ pk)
{
    int idx = blockIdx.x * 256 + threadIdx.x;   // 0 .. 98303
    int j = idx & 7;
    int t = idx >> 3;
    int ln = t & 63; t >>= 6;
    int c  = t & 3;  t >>= 2;
    int q  = t & 3;  t >>= 2;
    int l  = t % 3;
    int w  = t / 3;
    int row = q * 64 + w * 16 + (ln & 15);
    int k   = c * 32 + ((ln >> 4) << 3) + j;
    float val = 0.f;
    if (l == 0) {
        if (k < 8)                 val = Wih0[row * 8 + k];
        else if (k >= 32 && k < 96) val = Whh0[row * 64 + (k - 32)];
    } else if (l == 1) {
        val = (k < 64) ? Wih1[row * 64 + k] : Whh1[row * 64 + (k - 64)];
    } else {
        val = (k < 64) ? Wih2[row * 64 + k] : Whh2[row * 64 + (k - 64)];
    }
    pk[idx] = (f16)val;
}

__device__ __forceinline__ float sigf(float x)      { return 1.f / (1.f + __expf(-x)); }
__device__ __forceinline__ float tanhfast(float x)  { return 1.f - 2.f / (__expf(2.f * x) + 1.f); }
__device__ __forceinline__ float softplusf(float x) { return fmaxf(x, 0.f) + log1pf(__expf(-fabsf(x))); }

// ---------------------------------------------------------------------------
// Main kernel: 256 WGs x 256 threads. WG owns 16 batches; wave w owns hid
// block [w*16, w*16+16). Weights live in VGPRs for the whole kernel.
// h double-buffered in LDS (parity pp = step&1); x staged in LDS (K padded
// to 32 with zeros). MFMA 16x16x32 f16, fp32 accumulate, fp32 cell state.
// ---------------------------------------------------------------------------
__global__ __launch_bounds__(256, 1) void lstm_kernel(
    const float* __restrict__ enc_x, const float* __restrict__ enc_z,
    const float* __restrict__ dec_x, const float* __restrict__ v,
    const float* __restrict__ eps,   const f16* __restrict__ pk,
    const float* __restrict__ b0, const float* __restrict__ b1,
    const float* __restrict__ b2,
    const float* __restrict__ w_m, const float* __restrict__ b_m,
    const float* __restrict__ w_a, const float* __restrict__ b_a,
    float* __restrict__ out)
{
    const int tid  = threadIdx.x;
    const int lane = tid & 63;
    const int wv   = tid >> 6;
    const int bg   = blockIdx.x * 16;
    const int m16  = lane & 15;     // A-row index / C-col index
    const int quad = lane >> 4;

    __shared__ f16  hbuf[2][3][16][HSTR];   // [parity][layer][batch][hid]
    __shared__ f16  xbuf[16][32];           // layer0 input, k>=8 stays 0
    __shared__ float zbuf[16];

    // ---- zero LDS (xbuf pad + initial h state) ----
    {
        uint* hz = (uint*)&hbuf[0][0][0][0];
        const int HW = 2 * 3 * 16 * HSTR / 2;   // 3456 u32 words
        for (int i = tid; i < HW; i += 256) hz[i] = 0u;
        ((uint*)&xbuf[0][0])[tid] = 0u;         // 256 words exactly
    }

    // ---- load weight fragments into registers (loop-invariant) ----
    f16x8 wgt[3][4][4];                     // [layer][q(gate)][chunk]
#pragma unroll
    for (int l = 0; l < 3; ++l)
#pragma unroll
        for (int q = 0; q < 4; ++q)
#pragma unroll
            for (int c = 0; c < 4; ++c) {
                if (l == 0 && c == 3) continue;   // unused slot
                size_t off = (((((size_t)wv * 3 + l) * 4 + q) * 4 + c) * 64 + lane) * 8;
                wgt[l][q][c] = *(const f16x8*)(pk + off);
            }

    float bias[3][4];
#pragma unroll
    for (int q = 0; q < 4; ++q) {
        bias[0][q] = b0[q * 64 + wv * 16 + m16];
        bias[1][q] = b1[q * 64 + wv * 16 + m16];
        bias[2][q] = b2[q * 64 + wv * 16 + m16];
    }

    f16* hb = &hbuf[0][0][0][0];
    const int aoff = m16 * HSTR + quad * 8;       // A-fragment read offset
    const int hid_self = wv * 16 + m16;
    float cst[3][4] = {};                         // fp32 cell state

#define HBASE(pp, l) (hb + ((pp) * 3 + (l)) * (16 * HSTR))

#define MFMA_CHUNK(aptr, l, c)                                                  \
    {                                                                           \
        f16x8 af = *(const f16x8*)(aptr);                                       \
        ac0 = __builtin_amdgcn_mfma_f32_16x16x32_f16(af, wgt[l][0][c], ac0, 0, 0, 0); \
        ac1 = __builtin_amdgcn_mfma_f32_16x16x32_f16(af, wgt[l][1][c], ac1, 0, 0, 0); \
        ac2 = __builtin_amdgcn_mfma_f32_16x16x32_f16(af, wgt[l][2][c], ac2, 0, 0, 0); \
        ac3 = __builtin_amdgcn_mfma_f32_16x16x32_f16(af, wgt[l][3][c], ac3, 0, 0, 0); \
    }

// C/D layout (m89-verified): lane holds rows (quad*4 + r), col = lane&15.
// ac0=i, ac1=f, ac2=g, ac3=o for (batch row, hid_self) -> in-lane cell update.
#define CELL_WRITE(l, pp)                                                       \
    {                                                                           \
        f16* hw = HBASE(pp, l) + hid_self;                                      \
        _Pragma("unroll")                                                       \
        for (int r = 0; r < 4; ++r) {                                           \
            float iv = sigf(ac0[r]);                                            \
            float fv = sigf(ac1[r]);                                            \
            float gv = tanhfast(ac2[r]);                                        \
            float ov = sigf(ac3[r]);                                            \
            float cn = fv * cst[l][r] + iv * gv;                                \
            cst[l][r] = cn;                                                     \
            hw[(quad * 4 + r) * HSTR] = (f16)(ov * tanhfast(cn));               \
        }                                                                       \
    }

#define LAYER0(pp)                                                              \
    {                                                                           \
        f32x4 ac0 = {bias[0][0], bias[0][0], bias[0][0], bias[0][0]};           \
        f32x4 ac1 = {bias[0][1], bias[0][1], bias[0][1], bias[0][1]};           \
        f32x4 ac2 = {bias[0][2], bias[0][2], bias[0][2], bias[0][2]};           \
        f32x4 ac3 = {bias[0][3], bias[0][3], bias[0][3], bias[0][3]};           \
        MFMA_CHUNK(&xbuf[0][0] + m16 * 32 + quad * 8, 0, 0);                    \
        MFMA_CHUNK(HBASE(1 - (pp), 0) + aoff + 0,  0, 1);                       \
        MFMA_CHUNK(HBASE(1 - (pp), 0) + aoff + 32, 0, 2);                       \
        CELL_WRITE(0, pp);                                                      \
    }

#define LAYER1(pp)                                                              \
    {                                                                           \
        f32x4 ac0 = {bias[1][0], bias[1][0], bias[1][0], bias[1][0]};           \
        f32x4 ac1 = {bias[1][1], bias[1][1], bias[1][1], bias[1][1]};           \
        f32x4 ac2 = {bias[1][2], bias[1][2], bias[1][2], bias[1][2]};           \
        f32x4 ac3 = {bias[1][3], bias[1][3], bias[1][3], bias[1][3]};           \
        MFMA_CHUNK(HBASE(pp, 0) + aoff + 0,  1, 0);                             \
        MFMA_CHUNK(HBASE(pp, 0) + aoff + 32, 1, 1);                             \
        MFMA_CHUNK(HBASE(1 - (pp), 1) + aoff + 0,  1, 2);                       \
        MFMA_CHUNK(HBASE(1 - (pp), 1) + aoff + 32, 1, 3);                       \
        CELL_WRITE(1, pp);                                                      \
    }

#define LAYER2(pp)                                                              \
    {                                                                           \
        f32x4 ac0 = {bias[2][0], bias[2][0], bias[2][0], bias[2][0]};           \
        f32x4 ac1 = {bias[2][1], bias[2][1], bias[2][1], bias[2][1]};           \
        f32x4 ac2 = {bias[2][2], bias[2][2], bias[2][2], bias[2][2]};           \
        f32x4 ac3 = {bias[2][3], bias[2][3], bias[2][3], bias[2][3]};           \
        MFMA_CHUNK(HBASE(pp, 1) + aoff + 0,  2, 0);                             \
        MFMA_CHUNK(HBASE(pp, 1) + aoff + 32, 2, 1);                             \
        MFMA_CHUNK(HBASE(1 - (pp), 2) + aoff + 0,  2, 2);                       \
        MFMA_CHUNK(HBASE(1 - (pp), 2) + aoff + 32, 2, 3);                       \
        CELL_WRITE(2, pp);                                                      \
    }

    const int  mS   = tid >> 3, kS = tid & 7;
    const bool isst = tid < 128;

    __syncthreads();   // LDS zero-init visible before any staging writes

    // ---------------- encoder ----------------
    float xpre = 0.f;
    if (isst) xpre = enc_x[((size_t)(bg + mS) * TE + 0) * 8 + kS];
    for (int t = 0; t < TE; ++t) {
        const int pp = t & 1;
        if (isst) xbuf[mS][kS] = (f16)xpre;
        __syncthreads();
        if (isst && t + 1 < TE)                   // prefetch next step's x
            xpre = enc_x[((size_t)(bg + mS) * TE + (t + 1)) * 8 + kS];
        LAYER0(pp); __syncthreads();
        LAYER1(pp); __syncthreads();
        LAYER2(pp);
        // no barrier: next iteration's stage/L0/L1 barriers cover h2 hazards
    }

    // ---------------- decoder ----------------
    const int   mH = tid >> 4;            // head batch (16 threads each)
    const float vf = v[bg + mH];
    float wmr[4], war[4];
#pragma unroll
    for (int r = 0; r < 4; ++r) {
        wmr[r] = w_m[(tid & 15) + 16 * r];
        war[r] = w_a[(tid & 15) + 16 * r];
    }
    const float bmv = b_m[0], bav = b_a[0];
    if ((tid & 15) == 0) zbuf[mH] = enc_z[(size_t)(bg + mH) * TE + (TE - 1)] / vf;

    for (int t = 0; t < TD; ++t) {
        const int pp = (TE + t) & 1;
        __syncthreads();                  // zbuf ready; xbuf free
        if (isst) {
            float xv = (kS == 0) ? zbuf[mS]
                                 : dec_x[((size_t)(bg + mS) * TD + t) * 7 + (kS - 1)];
            xbuf[mS][kS] = (f16)xv;
        }
        __syncthreads();
        LAYER0(pp); __syncthreads();
        LAYER1(pp); __syncthreads();
        LAYER2(pp); __syncthreads();

        // head: 16 threads per batch, each sums 4 hids, then 16-lane reduce
        float sm = 0.f, sa = 0.f;
        const f16* h2 = HBASE(pp, 2) + mH * HSTR;
#pragma unroll
        for (int r = 0; r < 4; ++r) {
            float hv = (float)h2[(tid & 15) + 16 * r];
            sm += hv * wmr[r];
            sa += hv * war[r];
        }
#pragma unroll
        for (int off = 1; off < 16; off <<= 1) {
            sm += __shfl_xor(sm, off, 64);
            sa += __shfl_xor(sa, off, 64);
        }
        if ((tid & 15) == 0) {
            float mo = (sm + bmv) * vf;
            float ao = softplusf(sa + bav) * vf;
            float zs = mo + ao * eps[(size_t)(bg + mH) * TD + t];
            out[(size_t)(bg + mH) * TD + t] = zs;
            zbuf[mH] = zs / vf;
        }
        // next-iteration top barrier covers zbuf / h2 hazards
    }

#undef HBASE
#undef MFMA_CHUNK
#undef CELL_WRITE
#undef LAYER0
#undef LAYER1
#undef LAYER2
}

extern "C" void kernel_launch(void* const* d_in, const int* in_sizes, int n_in,
                              void* d_out, int out_size, void* d_ws, size_t ws_size,
                              hipStream_t stream) {
    const float* enc_x = (const float*)d_in[0];
    const float* enc_z = (const float*)d_in[1];
    const float* dec_x = (const float*)d_in[2];
    const float* v     = (const float*)d_in[3];
    const float* eps   = (const float*)d_in[4];
    const float* Wih0  = (const float*)d_in[5];
    const float* Whh0  = (const float*)d_in[6];
    const float* b0    = (const float*)d_in[7];
    const float* Wih1  = (const float*)d_in[8];
    const float* Whh1  = (const float*)d_in[9];
    const float* b1    = (const float*)d_in[10];
    const float* Wih2  = (const float*)d_in[11];
    const float* Whh2  = (const float*)d_in[12];
    const float* b2    = (const float*)d_in[13];
    const float* w_m   = (const float*)d_in[14];
    const float* b_m   = (const float*)d_in[15];
    const float* w_a   = (const float*)d_in[16];
    const float* b_a   = (const float*)d_in[17];
    float* out = (float*)d_out;
    f16*   pk  = (f16*)d_ws;    // 192 KB of workspace

    pack_kernel<<<384, 256, 0, stream>>>(Wih0, Whh0, Wih1, Whh1, Wih2, Whh2, pk);
    lstm_kernel<<<NWG, 256, 0, stream>>>(enc_x, enc_z, dec_x, v, eps, pk,
                                         b0, b1, b2, w_m, b_m, w_a, b_a, out);
}

// Round 3
// 364.893 us; speedup vs baseline: 61.6486x; 1.6501x over previous
//
#include <hip/hip_runtime.h>
#include <math.h>

#define B_TOT 4096
#define TE 168
#define TD 24
#define NWG 256          // B_TOT / 16 batches per WG
#define HSTR 72          // padded f16 row stride (144 B, 16B-aligned)

typedef _Float16 f16;
typedef __attribute__((ext_vector_type(8))) _Float16 f16x8;
typedef __attribute__((ext_vector_type(4))) float f32x4;

// Activation pre-scaling folded into weights (and biases at load):
//   i,f,o gates: w *= -log2(e)   -> sigmoid(a) = rcp(1 + exp2(y)),  y = -a*log2e
//   g gate:      w *= +2*log2(e) -> tanh(a)    = 1 - 2*rcp(1 + exp2(z)), z = 2a*log2e
#define SCL_S (-1.4426950408889634f)
#define SCL_G (2.885390081777927f)

// ---------------------------------------------------------------------------
// Pack weights into exact MFMA B-fragment order, f16, pre-scaled per gate:
//   pk[w][l][q][c][lane][j] = scale_q * Wcomb_l[q*64 + w*16 + (lane&15)][c*32 + (lane>>4)*8 + j]
// Wcomb per layer (K padded to 32-multiples):
//   l=0 (K=96):  k<8 -> Wih0[.][k];  8<=k<32 -> 0;  32<=k<96 -> Whh0[.][k-32]
//   l=1 (K=128): k<64 -> Wih1[.][k];  else Whh1[.][k-64]
//   l=2 (K=128): k<64 -> Wih2[.][k];  else Whh2[.][k-64]
// ---------------------------------------------------------------------------
__global__ __launch_bounds__(256) void pack_kernel(
    const float* __restrict__ Wih0, const float* __restrict__ Whh0,
    const float* __restrict__ Wih1, const float* __restrict__ Whh1,
    const float* __restrict__ Wih2, const float* __restrict__ Whh2,
    f16* __restrict__ pk)
{
    int idx = blockIdx.x * 256 + threadIdx.x;   // 0 .. 98303
    int j = idx & 7;
    int t = idx >> 3;
    int ln = t & 63; t >>= 6;
    int c  = t & 3;  t >>= 2;
    int q  = t & 3;  t >>= 2;
    int l  = t % 3;
    int w  = t / 3;
    int row = q * 64 + w * 16 + (ln & 15);
    int k   = c * 32 + ((ln >> 4) << 3) + j;
    float val = 0.f;
    if (l == 0) {
        if (k < 8)                 val = Wih0[row * 8 + k];
        else if (k >= 32 && k < 96) val = Whh0[row * 64 + (k - 32)];
    } else if (l == 1) {
        val = (k < 64) ? Wih1[row * 64 + k] : Whh1[row * 64 + (k - 64)];
    } else {
        val = (k < 64) ? Wih2[row * 64 + k] : Whh2[row * 64 + (k - 64)];
    }
    const float sc = (q == 2) ? SCL_G : SCL_S;
    pk[idx] = (f16)(val * sc);
}

__device__ __forceinline__ float softplusf(float x) { return fmaxf(x, 0.f) + log1pf(__expf(-fabsf(x))); }

// ---------------------------------------------------------------------------
// Main kernel: 256 WGs x 256 threads. WG owns 16 batches; wave w owns hid
// block [w*16, w*16+16). Weights live in VGPR/AGPR for the whole kernel.
// Time loop unrolled x2 (compile-time parity -> immediate LDS offsets).
// Per step, the hh-half MFMAs of layer l+1 (which read the *previous* step's
// h, already visible) are issued before the barrier publishing layer l's
// output, overlapping cell-update trans latency with independent MFMA work.
// ---------------------------------------------------------------------------
__global__ __launch_bounds__(256, 1) void lstm_kernel(
    const float* __restrict__ enc_x, const float* __restrict__ enc_z,
    const float* __restrict__ dec_x, const float* __restrict__ v,
    const float* __restrict__ eps,   const f16* __restrict__ pk,
    const float* __restrict__ b0, const float* __restrict__ b1,
    const float* __restrict__ b2,
    const float* __restrict__ w_m, const float* __restrict__ b_m,
    const float* __restrict__ w_a, const float* __restrict__ b_a,
    float* __restrict__ out)
{
    const int tid  = threadIdx.x;
    const int lane = tid & 63;
    const int wv   = tid >> 6;
    const int bg   = blockIdx.x * 16;
    const int m16  = lane & 15;     // A-row index / C-col index
    const int quad = lane >> 4;

    __shared__ f16  hbuf[2][3][16][HSTR];   // [parity][layer][batch][hid]
    __shared__ f16  xbuf[16][32];           // layer0 input, k>=8 stays 0
    __shared__ float zbuf[16];

    // ---- zero LDS ----
    {
        uint* hz = (uint*)&hbuf[0][0][0][0];
        const int HW = 2 * 3 * 16 * HSTR / 2;
        for (int i = tid; i < HW; i += 256) hz[i] = 0u;
        ((uint*)&xbuf[0][0])[tid] = 0u;
    }

    // ---- weight fragments (loop-invariant) ----
    f16x8 wgt[3][4][4];
#pragma unroll
    for (int l = 0; l < 3; ++l)
#pragma unroll
        for (int q = 0; q < 4; ++q)
#pragma unroll
            for (int c = 0; c < 4; ++c) {
                if (l == 0 && c == 3) continue;
                size_t off = (((((size_t)wv * 3 + l) * 4 + q) * 4 + c) * 64 + lane) * 8;
                wgt[l][q][c] = *(const f16x8*)(pk + off);
            }

    const int hid_self = wv * 16 + m16;
    // ---- bias splats (pre-scaled), consumed as C of first MFMA per gate ----
    f32x4 bsp[3][4];
#pragma unroll
    for (int q = 0; q < 4; ++q) {
        const float sc = (q == 2) ? SCL_G : SCL_S;
        float v0 = b0[q * 64 + hid_self] * sc;
        float v1 = b1[q * 64 + hid_self] * sc;
        float v2 = b2[q * 64 + hid_self] * sc;
        bsp[0][q] = (f32x4){v0, v0, v0, v0};
        bsp[1][q] = (f32x4){v1, v1, v1, v1};
        bsp[2][q] = (f32x4){v2, v2, v2, v2};
    }

    f16* hb = &hbuf[0][0][0][0];
    const int aoff = m16 * HSTR + quad * 8;       // A-fragment lane offset
    float cst[3][4] = {};                         // fp32 cell state

#define HBASE(pp, l) (hb + ((pp) * 3 + (l)) * (16 * HSTR))
#define MFMA16(af, bf, cf) __builtin_amdgcn_mfma_f32_16x16x32_f16(af, bf, cf, 0, 0, 0)

#define MM_F(P, aptr, l, c)                                                   \
    {                                                                         \
        f16x8 af = *(const f16x8*)(aptr);                                     \
        P##0 = MFMA16(af, wgt[l][0][c], bsp[l][0]);                           \
        P##1 = MFMA16(af, wgt[l][1][c], bsp[l][1]);                           \
        P##2 = MFMA16(af, wgt[l][2][c], bsp[l][2]);                           \
        P##3 = MFMA16(af, wgt[l][3][c], bsp[l][3]);                           \
    }
#define MM(P, aptr, l, c)                                                     \
    {                                                                         \
        f16x8 af = *(const f16x8*)(aptr);                                     \
        P##0 = MFMA16(af, wgt[l][0][c], P##0);                                \
        P##1 = MFMA16(af, wgt[l][1][c], P##1);                                \
        P##2 = MFMA16(af, wgt[l][2][c], P##2);                                \
        P##3 = MFMA16(af, wgt[l][3][c], P##3);                                \
    }

// C/D layout (m89): lane holds rows quad*4+r, col = m16. acc0..3 = i,f,g,o
// pre-activations already scaled for exp2-form activations.
#define CELL(P, l, PP)                                                        \
    {                                                                         \
        f16* hw = HBASE(PP, l) + hid_self;                                    \
        _Pragma("unroll")                                                     \
        for (int r = 0; r < 4; ++r) {                                         \
            float iv = __builtin_amdgcn_rcpf(1.f + __builtin_amdgcn_exp2f(P##0[r])); \
            float fv = __builtin_amdgcn_rcpf(1.f + __builtin_amdgcn_exp2f(P##1[r])); \
            float gv = fmaf(-2.f, __builtin_amdgcn_rcpf(1.f + __builtin_amdgcn_exp2f(P##2[r])), 1.f); \
            float ov = __builtin_amdgcn_rcpf(1.f + __builtin_amdgcn_exp2f(P##3[r])); \
            float cn = fmaf(fv, cst[l][r], iv * gv);                          \
            cst[l][r] = cn;                                                   \
            float tc = fmaf(-2.f, __builtin_amdgcn_rcpf(1.f + __builtin_amdgcn_exp2f(cn * SCL_G)), 1.f); \
            hw[(quad * 4 + r) * HSTR] = (f16)(ov * tc);                       \
        }                                                                     \
    }

    const int  mS   = tid >> 3, kS = tid & 7;
    const bool isst = tid < 128;

#define ENC_STEP(PP, t)                                                       \
    {                                                                         \
        __syncthreads();  /* A: x(t), h*[1-PP] visible */                     \
        f32x4 ac0, ac1, ac2, ac3, bc0, bc1, bc2, bc3;                         \
        MM_F(ac, &xbuf[0][0] + m16 * 32 + quad * 8, 0, 0);                    \
        MM_F(bc, HBASE(1 - (PP), 1) + aoff, 1, 2);                            \
        MM(ac, HBASE(1 - (PP), 0) + aoff, 0, 1);                              \
        MM(bc, HBASE(1 - (PP), 1) + aoff + 32, 1, 3);                         \
        MM(ac, HBASE(1 - (PP), 0) + aoff + 32, 0, 2);                         \
        CELL(ac, 0, PP);                                                      \
        __syncthreads();  /* B: h0[PP] visible; xbuf free */                  \
        if (isst && (t) + 1 < TE) {                                           \
            xbuf[mS][kS] = (f16)xpre;                                         \
            if ((t) + 2 < TE)                                                 \
                xpre = enc_x[((size_t)(bg + mS) * TE + (t) + 2) * 8 + kS];    \
        }                                                                     \
        MM_F(ac, HBASE(1 - (PP), 2) + aoff, 2, 2);                            \
        MM(bc, HBASE(PP, 0) + aoff, 1, 0);                                    \
        MM(ac, HBASE(1 - (PP), 2) + aoff + 32, 2, 3);                         \
        MM(bc, HBASE(PP, 0) + aoff + 32, 1, 1);                               \
        CELL(bc, 1, PP);                                                      \
        __syncthreads();  /* C: h1[PP] visible */                             \
        MM(ac, HBASE(PP, 1) + aoff, 2, 0);                                    \
        MM(ac, HBASE(PP, 1) + aoff + 32, 2, 1);                               \
        CELL(ac, 2, PP);                                                      \
    }

    __syncthreads();   // LDS zero-init visible

    // ---------------- encoder ----------------
    float xpre = 0.f;
    if (isst) {
        xbuf[mS][kS] = (f16)enc_x[((size_t)(bg + mS) * TE + 0) * 8 + kS];
        xpre = enc_x[((size_t)(bg + mS) * TE + 1) * 8 + kS];
    }
    for (int t = 0; t < TE; t += 2) {
        ENC_STEP(0, t)
        ENC_STEP(1, t + 1)
    }

    // ---------------- decoder ----------------
    const int   mH = tid >> 4;            // head batch (16 threads each)
    const float vf = v[bg + mH];
    float wmr[4], war[4];
#pragma unroll
    for (int r = 0; r < 4; ++r) {
        wmr[r] = w_m[(tid & 15) + 16 * r];
        war[r] = w_a[(tid & 15) + 16 * r];
    }
    const float bmv = b_m[0], bav = b_a[0];
    if ((tid & 15) == 0) zbuf[mH] = enc_z[(size_t)(bg + mH) * TE + (TE - 1)] / vf;

#define DEC_STEP(PP, t)                                                       \
    {                                                                         \
        __syncthreads();  /* A: zbuf + prev h visible */                      \
        if (isst) {                                                           \
            float xv = (kS == 0) ? zbuf[mS]                                   \
                                 : dec_x[((size_t)(bg + mS) * TD + (t)) * 7 + (kS - 1)]; \
            xbuf[mS][kS] = (f16)xv;                                           \
        }                                                                     \
        __syncthreads();  /* A2: x(t) visible */                              \
        f32x4 ac0, ac1, ac2, ac3, bc0, bc1, bc2, bc3;                         \
        MM_F(ac, &xbuf[0][0] + m16 * 32 + quad * 8, 0, 0);                    \
        MM_F(bc, HBASE(1 - (PP), 1) + aoff, 1, 2);                            \
        MM(ac, HBASE(1 - (PP), 0) + aoff, 0, 1);                              \
        MM(bc, HBASE(1 - (PP), 1) + aoff + 32, 1, 3);                         \
        MM(ac, HBASE(1 - (PP), 0) + aoff + 32, 0, 2);                         \
        CELL(ac, 0, PP);                                                      \
        __syncthreads();  /* B */                                             \
        MM_F(ac, HBASE(1 - (PP), 2) + aoff, 2, 2);                            \
        MM(bc, HBASE(PP, 0) + aoff, 1, 0);                                    \
        MM(ac, HBASE(1 - (PP), 2) + aoff + 32, 2, 3);                         \
        MM(bc, HBASE(PP, 0) + aoff + 32, 1, 1);                               \
        CELL(bc, 1, PP);                                                      \
        __syncthreads();  /* C */                                             \
        MM(ac, HBASE(PP, 1) + aoff, 2, 0);                                    \
        MM(ac, HBASE(PP, 1) + aoff + 32, 2, 1);                               \
        CELL(ac, 2, PP);                                                      \
        __syncthreads();  /* D: h2[PP] visible */                             \
        {                                                                     \
            float sm = 0.f, sa = 0.f;                                         \
            const f16* h2p = HBASE(PP, 2) + mH * HSTR;                        \
            _Pragma("unroll")                                                 \
            for (int r = 0; r < 4; ++r) {                                     \
                float hv = (float)h2p[(tid & 15) + 16 * r];                   \
                sm += hv * wmr[r];                                            \
                sa += hv * war[r];                                            \
            }                                                                 \
            _Pragma("unroll")                                                 \
            for (int off = 1; off < 16; off <<= 1) {                          \
                sm += __shfl_xor(sm, off, 64);                                \
                sa += __shfl_xor(sa, off, 64);                                \
            }                                                                 \
            if ((tid & 15) == 0) {                                            \
                float mo  = (sm + bmv) * vf;                                  \
                float ao  = softplusf(sa + bav) * vf;                         \
                float zsv = mo + ao * eps[(size_t)(bg + mH) * TD + (t)];      \
                out[(size_t)(bg + mH) * TD + (t)] = zsv;                      \
                zbuf[mH] = zsv / vf;                                          \
            }                                                                 \
        }                                                                     \
    }

    for (int t = 0; t < TD; t += 2) {   // parity continues: (TE+t)&1 == t&1
        DEC_STEP(0, t)
        DEC_STEP(1, t + 1)
    }

#undef HBASE
#undef MFMA16
#undef MM_F
#undef MM
#undef CELL
#undef ENC_STEP
#undef DEC_STEP
}

extern "C" void kernel_launch(void* const* d_in, const int* in_sizes, int n_in,
                              void* d_out, int out_size, void* d_ws, size_t ws_size,
                              hipStream_t stream) {
    const float* enc_x = (const float*)d_in[0];
    const float* enc_z = (const float*)d_in[1];
    const float* dec_x = (const float*)d_in[2];
    const float* v     = (const float*)d_in[3];
    const float* eps   = (const float*)d_in[4];
    const float* Wih0  = (const float*)d_in[5];
    const float* Whh0  = (const float*)d_in[6];
    const float* b0    = (const float*)d_in[7];
    const float* Wih1  = (const float*)d_in[8];
    const float* Whh1  = (const float*)d_in[9];
    const float* b1    = (const float*)d_in[10];
    const float* Wih2  = (const float*)d_in[11];
    const float* Whh2  = (const float*)d_in[12];
    const float* b2    = (const float*)d_in[13];
    const float* w_m   = (const float*)d_in[14];
    const float* b_m   = (const float*)d_in[15];
    const float* w_a   = (const float*)d_in[16];
    const float* b_a   = (const float*)d_in[17];
    float* out = (float*)d_out;
    f16*   pk  = (f16*)d_ws;    // 192 KB of workspace

    pack_kernel<<<384, 256, 0, stream>>>(Wih0, Whh0, Wih1, Whh1, Wih2, Whh2, pk);
    lstm_kernel<<<NWG, 256, 0, stream>>>(enc_x, enc_z, dec_x, v, eps, pk,
                                         b0, b1, b2, w_m, b_m, w_a, b_a, out);
}

// Round 4
// 339.130 us; speedup vs baseline: 66.3319x; 1.0760x over previous
//
#include <hip/hip_runtime.h>
#include <math.h>

#define B_TOT 4096
#define TE 168
#define TD 24
#define NWG 256          // B_TOT / 16 batches per WG
#define HSTR 72          // padded f16 row stride (144 B, 16B-aligned)

typedef _Float16 f16;
typedef __attribute__((ext_vector_type(8))) _Float16 f16x8;
typedef __attribute__((ext_vector_type(4))) float f32x4;

// Activation pre-scaling folded into weights/biases:
//   i,f,o: w *= -log2(e)  -> E = exp2(y) = e^{-x}; sigmoid = 1/(1+E)
//   g:     w *= 2*log2(e) -> E = e^{2x};  tanh = (E-1)/(E+1)
#define SCL_S (-1.4426950408889634f)
#define SCL_G (2.885390081777927f)

// ---------------------------------------------------------------------------
// Pack weights into MFMA B-fragment order, f16, pre-scaled per gate:
//   pk[w][l][q][c][lane][j] = scale_q * Wcomb_l[q*64+w*16+(lane&15)][c*32+(lane>>4)*8+j]
//   l=0 (K=96):  k<8 -> Wih0; 8..31 -> 0; 32..95 -> Whh0[k-32]
//   l=1 (K=128): k<64 -> Wih1 (input h0); else Whh1[k-64] (recurrent h1)
//   l=2 (K=128): k<64 -> Wih2 (input h1); else Whh2[k-64] (recurrent h2)
// ---------------------------------------------------------------------------
__global__ __launch_bounds__(256) void pack_kernel(
    const float* __restrict__ Wih0, const float* __restrict__ Whh0,
    const float* __restrict__ Wih1, const float* __restrict__ Whh1,
    const float* __restrict__ Wih2, const float* __restrict__ Whh2,
    f16* __restrict__ pk)
{
    int idx = blockIdx.x * 256 + threadIdx.x;   // 0 .. 98303
    int j = idx & 7;
    int t = idx >> 3;
    int ln = t & 63; t >>= 6;
    int c  = t & 3;  t >>= 2;
    int q  = t & 3;  t >>= 2;
    int l  = t % 3;
    int w  = t / 3;
    int row = q * 64 + w * 16 + (ln & 15);
    int k   = c * 32 + ((ln >> 4) << 3) + j;
    float val = 0.f;
    if (l == 0) {
        if (k < 8)                 val = Wih0[row * 8 + k];
        else if (k >= 32 && k < 96) val = Whh0[row * 64 + (k - 32)];
    } else if (l == 1) {
        val = (k < 64) ? Wih1[row * 64 + k] : Whh1[row * 64 + (k - 64)];
    } else {
        val = (k < 64) ? Wih2[row * 64 + k] : Whh2[row * 64 + (k - 64)];
    }
    const float sc = (q == 2) ? SCL_G : SCL_S;
    pk[idx] = (f16)(val * sc);
}

__device__ __forceinline__ float softplusf(float x) { return fmaxf(x, 0.f) + log1pf(__expf(-fabsf(x))); }

// ---------------------------------------------------------------------------
// 256 WGs x 256 threads; WG owns 16 batches; wave w owns hid block w*16..+16.
// Weights in VGPRs. ENCODER is layer-pipelined (systolic skew): round r
// computes L0(t=r), L1(r-1), L2(r-2); all reads from parity 1-pp, writes to
// pp -> ONE barrier per round, 3 independent MFMA+trans chains per wave.
// DECODER is serial (z feedback), per-layer parities tracked explicitly.
// ---------------------------------------------------------------------------
__global__ __launch_bounds__(256, 1) void lstm_kernel(
    const float* __restrict__ enc_x, const float* __restrict__ enc_z,
    const float* __restrict__ dec_x, const float* __restrict__ v,
    const float* __restrict__ eps,   const f16* __restrict__ pk,
    const float* __restrict__ b0, const float* __restrict__ b1,
    const float* __restrict__ b2,
    const float* __restrict__ w_m, const float* __restrict__ b_m,
    const float* __restrict__ w_a, const float* __restrict__ b_a,
    float* __restrict__ out)
{
    const int tid  = threadIdx.x;
    const int lane = tid & 63;
    const int wv   = tid >> 6;
    const int bg   = blockIdx.x * 16;
    const int m16  = lane & 15;
    const int quad = lane >> 4;

    __shared__ f16  hbuf[2][3][16][HSTR];   // [parity][layer][batch][hid]
    __shared__ f16  xbuf[2][16][32];        // [parity][batch][k] (k>=8 stays 0)
    __shared__ float zbuf[16];

    // ---- zero LDS ----
    {
        uint* hz = (uint*)&hbuf[0][0][0][0];
        const int HW = 2 * 3 * 16 * HSTR / 2;
        for (int i = tid; i < HW; i += 256) hz[i] = 0u;
        uint* xz = (uint*)&xbuf[0][0][0];
        for (int i = tid; i < 512; i += 256) xz[i] = 0u;
    }

    // ---- weight fragments (loop-invariant, VGPR-resident) ----
    f16x8 wgt[3][4][4];
#pragma unroll
    for (int l = 0; l < 3; ++l)
#pragma unroll
        for (int q = 0; q < 4; ++q)
#pragma unroll
            for (int c = 0; c < 4; ++c) {
                if (l == 0 && c == 3) continue;
                size_t off = (((((size_t)wv * 3 + l) * 4 + q) * 4 + c) * 64 + lane) * 8;
                wgt[l][q][c] = *(const f16x8*)(pk + off);
            }

    const int hid_self = wv * 16 + m16;
    f32x4 bsp[3][4];
#pragma unroll
    for (int q = 0; q < 4; ++q) {
        const float sc = (q == 2) ? SCL_G : SCL_S;
        float v0 = b0[q * 64 + hid_self] * sc;
        float v1 = b1[q * 64 + hid_self] * sc;
        float v2 = b2[q * 64 + hid_self] * sc;
        bsp[0][q] = (f32x4){v0, v0, v0, v0};
        bsp[1][q] = (f32x4){v1, v1, v1, v1};
        bsp[2][q] = (f32x4){v2, v2, v2, v2};
    }

    f16* hb = &hbuf[0][0][0][0];
    const int aoff = m16 * HSTR + quad * 8;
    float cst[3][4] = {};

#define HBASE(pp, l) (hb + ((pp) * 3 + (l)) * (16 * HSTR))
#define MFMA16(af, bf, cf) __builtin_amdgcn_mfma_f32_16x16x32_f16(af, bf, cf, 0, 0, 0)

#define MM_F(P, aptr, l, c)                                                   \
    {                                                                         \
        f16x8 af = *(const f16x8*)(aptr);                                     \
        P##0 = MFMA16(af, wgt[l][0][c], bsp[l][0]);                           \
        P##1 = MFMA16(af, wgt[l][1][c], bsp[l][1]);                           \
        P##2 = MFMA16(af, wgt[l][2][c], bsp[l][2]);                           \
        P##3 = MFMA16(af, wgt[l][3][c], bsp[l][3]);                           \
    }
#define MM(P, aptr, l, c)                                                     \
    {                                                                         \
        f16x8 af = *(const f16x8*)(aptr);                                     \
        P##0 = MFMA16(af, wgt[l][0][c], P##0);                                \
        P##1 = MFMA16(af, wgt[l][1][c], P##1);                                \
        P##2 = MFMA16(af, wgt[l][2][c], P##2);                                \
        P##3 = MFMA16(af, wgt[l][3][c], P##3);                                \
    }

// Merged-rcp cell: i*g = (Eg-1)*rcp((1+Ei)(1+Eg)); o*tanh(c) =
// (Ec-1)*rcp((1+Eo)(1+Ec)). 5 exp2 + 3 rcp per output (was 5+5).
// C/D layout: lane -> col(hid)=m16, rows(batch)=quad*4+r.
#define CELL(P, l, PP)                                                        \
    {                                                                         \
        f16* hw = HBASE(PP, l) + hid_self;                                    \
        _Pragma("unroll")                                                     \
        for (int r = 0; r < 4; ++r) {                                         \
            float Ei = __builtin_amdgcn_exp2f(P##0[r]);                       \
            float Ef = __builtin_amdgcn_exp2f(P##1[r]);                       \
            float Eg = __builtin_amdgcn_exp2f(P##2[r]);                       \
            float Eo = __builtin_amdgcn_exp2f(P##3[r]);                       \
            float fv  = __builtin_amdgcn_rcpf(1.f + Ef);                      \
            float Rig = __builtin_amdgcn_rcpf((1.f + Ei) * (1.f + Eg));       \
            float cn  = fmaf(fv, cst[l][r], (Eg - 1.f) * Rig);                \
            cst[l][r] = cn;                                                   \
            float Ec  = __builtin_amdgcn_exp2f(cn * SCL_G);                   \
            float Roc = __builtin_amdgcn_rcpf((1.f + Eo) * (1.f + Ec));       \
            hw[(quad * 4 + r) * HSTR] = (f16)((Ec - 1.f) * Roc);              \
        }                                                                     \
    }

    const int  mS   = tid >> 3, kS = tid & 7;
    const bool isst = tid < 128;

// One pipelined encoder round, parity PP. D0/D1/D2: layer-active literals.
// DS: stage x(T0+1) from xpre into xbuf[1-PP]; DP: prefetch x(T0+2).
#define ROUND(PP, D0, D1, D2, DS, DP, T0)                                     \
    {                                                                         \
        __syncthreads();                                                      \
        f32x4 a00, a01, a02, a03, a10, a11, a12, a13, a20, a21, a22, a23;     \
        if (D0) {                                                             \
            MM_F(a0, &xbuf[PP][0][0] + m16 * 32 + quad * 8, 0, 0);            \
            MM(a0, HBASE(1 - (PP), 0) + aoff,      0, 1);                     \
            MM(a0, HBASE(1 - (PP), 0) + aoff + 32, 0, 2);                     \
        }                                                                     \
        if (D1) {                                                             \
            MM_F(a1, HBASE(1 - (PP), 0) + aoff,      1, 0);                   \
            MM(a1, HBASE(1 - (PP), 0) + aoff + 32, 1, 1);                     \
            MM(a1, HBASE(1 - (PP), 1) + aoff,      1, 2);                     \
            MM(a1, HBASE(1 - (PP), 1) + aoff + 32, 1, 3);                     \
        }                                                                     \
        if (D2) {                                                             \
            MM_F(a2, HBASE(1 - (PP), 1) + aoff,      2, 0);                   \
            MM(a2, HBASE(1 - (PP), 1) + aoff + 32, 2, 1);                     \
            MM(a2, HBASE(1 - (PP), 2) + aoff,      2, 2);                     \
            MM(a2, HBASE(1 - (PP), 2) + aoff + 32, 2, 3);                     \
        }                                                                     \
        if (DS && isst) {                                                     \
            xbuf[1 - (PP)][mS][kS] = (f16)xpre;                               \
            if (DP) xpre = enc_x[((size_t)(bg + mS) * TE + (T0) + 2) * 8 + kS]; \
        }                                                                     \
        if (D0) CELL(a0, 0, PP);                                              \
        if (D1) CELL(a1, 1, PP);                                              \
        if (D2) CELL(a2, 2, PP);                                              \
    }

    __syncthreads();   // zero-init visible

    // ---------------- encoder (layer-pipelined) ----------------
    float xpre = 0.f;
    if (isst) {
        xbuf[0][mS][kS] = (f16)enc_x[((size_t)(bg + mS) * TE + 0) * 8 + kS];
        xpre = enc_x[((size_t)(bg + mS) * TE + 1) * 8 + kS];
    }
    ROUND(0, 1, 0, 0, 1, 1, 0)           // r=0: L0(0)
    ROUND(1, 1, 1, 0, 1, 1, 1)           // r=1: L0(1), L1(0)
    for (int t = 2; t < 166; t += 2) {   // rounds 2..165 dense
        ROUND(0, 1, 1, 1, 1, 1, t)
        ROUND(1, 1, 1, 1, 1, 1, t + 1)
    }
    ROUND(0, 1, 1, 1, 1, 0, 166)         // r=166: stage x(167), no prefetch
    ROUND(1, 1, 1, 1, 0, 0, 167)         // r=167: last L0
    ROUND(0, 0, 1, 1, 0, 0, 168)         // r=168: L1(167), L2(166)
    ROUND(1, 0, 0, 1, 0, 0, 169)         // r=169: L2(167)
    // exit parities: h0(167)->buf1, h1(167)->buf0, h2(167)->buf1

    // ---------------- decoder (serial; z feedback) ----------------
    const int   mH = tid >> 4;
    const float vf = v[bg + mH];
    float wmr[4], war[4];
#pragma unroll
    for (int r = 0; r < 4; ++r) {
        wmr[r] = w_m[(tid & 15) + 16 * r];
        war[r] = w_a[(tid & 15) + 16 * r];
    }
    const float bmv = b_m[0], bav = b_a[0];
    if ((tid & 15) == 0) zbuf[mH] = enc_z[(size_t)(bg + mH) * TE + (TE - 1)] / vf;

// Parities per step t (PA = t&1): L0 reads h0[1-PA] writes [PA];
// L1 reads h0[PA]+h1[PA] writes h1[1-PA]; L2 reads h1[1-PA]+h2[1-PA]
// writes h2[PA]; head reads h2[PA]. Matches encoder exit at t=0 (PA=0).
#define DEC_STEP(PA, t)                                                       \
    {                                                                         \
        __syncthreads();  /* prev-step h + zbuf visible */                    \
        if (isst) {                                                           \
            float xv = (kS == 0) ? zbuf[mS]                                   \
                                 : dec_x[((size_t)(bg + mS) * TD + (t)) * 7 + (kS - 1)]; \
            xbuf[PA][mS][kS] = (f16)xv;                                       \
        }                                                                     \
        __syncthreads();  /* x visible */                                     \
        f32x4 ac0, ac1, ac2, ac3, bc0, bc1, bc2, bc3;                         \
        MM_F(ac, &xbuf[PA][0][0] + m16 * 32 + quad * 8, 0, 0);                \
        MM_F(bc, HBASE(PA, 1) + aoff,      1, 2);                             \
        MM(ac, HBASE(1 - (PA), 0) + aoff,      0, 1);                         \
        MM(bc, HBASE(PA, 1) + aoff + 32, 1, 3);                               \
        MM(ac, HBASE(1 - (PA), 0) + aoff + 32, 0, 2);                         \
        CELL(ac, 0, PA);                                                      \
        __syncthreads();  /* h0[PA] visible */                                \
        MM_F(ac, HBASE(1 - (PA), 2) + aoff,      2, 2);                       \
        MM(bc, HBASE(PA, 0) + aoff,      1, 0);                               \
        MM(ac, HBASE(1 - (PA), 2) + aoff + 32, 2, 3);                         \
        MM(bc, HBASE(PA, 0) + aoff + 32, 1, 1);                               \
        CELL(bc, 1, 1 - (PA));                                                \
        __syncthreads();  /* h1[1-PA] visible */                              \
        MM(ac, HBASE(1 - (PA), 1) + aoff,      2, 0);                         \
        MM(ac, HBASE(1 - (PA), 1) + aoff + 32, 2, 1);                         \
        CELL(ac, 2, PA);                                                      \
        __syncthreads();  /* h2[PA] visible */                                \
        {                                                                     \
            float sm = 0.f, sa = 0.f;                                         \
            const f16* h2p = HBASE(PA, 2) + mH * HSTR;                        \
            _Pragma("unroll")                                                 \
            for (int r = 0; r < 4; ++r) {                                     \
                float hv = (float)h2p[(tid & 15) + 16 * r];                   \
                sm += hv * wmr[r];                                            \
                sa += hv * war[r];                                            \
            }                                                                 \
            _Pragma("unroll")                                                 \
            for (int off = 1; off < 16; off <<= 1) {                          \
                sm += __shfl_xor(sm, off, 64);                                \
                sa += __shfl_xor(sa, off, 64);                                \
            }                                                                 \
            if ((tid & 15) == 0) {                                            \
                float mo  = (sm + bmv) * vf;                                  \
                float ao  = softplusf(sa + bav) * vf;                         \
                float zsv = mo + ao * eps[(size_t)(bg + mH) * TD + (t)];      \
                out[(size_t)(bg + mH) * TD + (t)] = zsv;                      \
                zbuf[mH] = zsv / vf;                                          \
            }                                                                 \
        }                                                                     \
    }

    for (int t = 0; t < TD; t += 2) {
        DEC_STEP(0, t)
        DEC_STEP(1, t + 1)
    }

#undef HBASE
#undef MFMA16
#undef MM_F
#undef MM
#undef CELL
#undef ROUND
#undef DEC_STEP
}

extern "C" void kernel_launch(void* const* d_in, const int* in_sizes, int n_in,
                              void* d_out, int out_size, void* d_ws, size_t ws_size,
                              hipStream_t stream) {
    const float* enc_x = (const float*)d_in[0];
    const float* enc_z = (const float*)d_in[1];
    const float* dec_x = (const float*)d_in[2];
    const float* v     = (const float*)d_in[3];
    const float* eps   = (const float*)d_in[4];
    const float* Wih0  = (const float*)d_in[5];
    const float* Whh0  = (const float*)d_in[6];
    const float* b0    = (const float*)d_in[7];
    const float* Wih1  = (const float*)d_in[8];
    const float* Whh1  = (const float*)d_in[9];
    const float* b1    = (const float*)d_in[10];
    const float* Wih2  = (const float*)d_in[11];
    const float* Whh2  = (const float*)d_in[12];
    const float* b2    = (const float*)d_in[13];
    const float* w_m   = (const float*)d_in[14];
    const float* b_m   = (const float*)d_in[15];
    const float* w_a   = (const float*)d_in[16];
    const float* b_a   = (const float*)d_in[17];
    float* out = (float*)d_out;
    f16*   pk  = (f16*)d_ws;

    pack_kernel<<<384, 256, 0, stream>>>(Wih0, Whh0, Wih1, Whh1, Wih2, Whh2, pk);
    lstm_kernel<<<NWG, 256, 0, stream>>>(enc_x, enc_z, dec_x, v, eps, pk,
                                         b0, b1, b2, w_m, b_m, w_a, b_a, out);
}